// Round 2
// baseline (123.080 us; speedup 1.0000x reference)
//
#include <hip/hip_runtime.h>
#include <hip/hip_bf16.h>
#include <hip/hip_fp16.h>

// Problem constants (fixed by setup_inputs)
#define NROWS 4096
#define IDIM  512
#define HDIM  2048
#define ODIM  512
#define NG    8      // groups (prefix structure)
#define NCH   8      // H chunks
#define HC    256    // H per chunk
#define TM    128    // rows per main block (32x32 MFMA structure)

typedef __attribute__((ext_vector_type(8))) short short8;   // 8 bf16
typedef __attribute__((ext_vector_type(4))) float f32x4;
typedef __attribute__((ext_vector_type(16))) float f32x16;

__device__ __forceinline__ unsigned short f2bf(float f) {
    unsigned int u = __float_as_uint(f);
    unsigned int r = (u + 0x7fffu + ((u >> 16) & 1u)) >> 16;
    return (unsigned short)r;
}

// async global->LDS, 16B per lane; lds base must be wave-uniform (HW adds lane*16)
__device__ __forceinline__ void glds16(const unsigned short* g, unsigned short* l) {
    __builtin_amdgcn_global_load_lds(
        (const __attribute__((address_space(1))) unsigned int*)g,
        (__attribute__((address_space(3))) unsigned int*)l, 16, 0, 0);
}

// ---- Prep kernel: fused x-convert + W1/W2 transpose-convert ----
__global__ __launch_bounds__(256) void k_prep(const float* __restrict__ x,
                                              const float* __restrict__ W1,
                                              const float* __restrict__ W2,
                                              unsigned short* __restrict__ xb,
                                              unsigned short* __restrict__ w1t,
                                              unsigned short* __restrict__ w2t) {
    __shared__ float tile[64 * 68];
    const int bz = blockIdx.x;
    const int t = threadIdx.x;
    if (bz < 1024) {
        int gt = bz * 256 + t;                    // x: 262144 threads, 8 floats each
        const float4* src = reinterpret_cast<const float4*>(x) + (size_t)gt * 2;
        float4 a = src[0], b = src[1];
        unsigned short o[8] = { f2bf(a.x), f2bf(a.y), f2bf(a.z), f2bf(a.w),
                                f2bf(b.x), f2bf(b.y), f2bf(b.z), f2bf(b.w) };
        *reinterpret_cast<uint4*>(xb + (size_t)gt * 8) = *reinterpret_cast<uint4*>(o);
        return;
    }
    int b = bz - 1024;
    const float* in;
    unsigned short* out;
    int R, C, c0, r0;
    if (b < 256) {            // W1: 512x2048 -> w1t[2048][512]
        in = W1; out = w1t; R = 512; C = 2048;
        c0 = (b & 31) * 64; r0 = (b >> 5) * 64;
    } else {                  // W2: 2048x512 -> w2t[512][2048]
        b -= 256;
        in = W2; out = w2t; R = 2048; C = 512;
        c0 = (b & 7) * 64; r0 = (b >> 3) * 64;
    }
    const int tx = t & 15, ty = t >> 4;
    #pragma unroll
    for (int p = 0; p < 4; ++p) {
        int rr = p * 16 + ty;
        float4 v = *reinterpret_cast<const float4*>(&in[(size_t)(r0 + rr) * C + c0 + tx * 4]);
        tile[rr * 68 + tx * 4 + 0] = v.x;
        tile[rr * 68 + tx * 4 + 1] = v.y;
        tile[rr * 68 + tx * 4 + 2] = v.z;
        tile[rr * 68 + tx * 4 + 3] = v.w;
    }
    __syncthreads();
    #pragma unroll
    for (int p = 0; p < 4; ++p) {
        int rr = p * 16 + ty;
        int cc = tx * 4;
        ushort4 o;
        o.x = f2bf(tile[(cc + 0) * 68 + rr]);
        o.y = f2bf(tile[(cc + 1) * 68 + rr]);
        o.z = f2bf(tile[(cc + 2) * 68 + rr]);
        o.w = f2bf(tile[(cc + 3) * 68 + rr]);
        *reinterpret_cast<ushort4*>(&out[(size_t)(c0 + rr) * R + r0 + cc]) = o;
    }
}

// ---- Kernel 1: fused prefix-GEMM1^T + relu + GEMM2 partials (fp16) ----
// 32x32x16 MFMA restructure: block = 128 samples x 1 chunk, grid (8,32)=256
// blocks = 1/CU, 8 waves. LDS 112KB (sX 16K + sW 32K + sH 64K).
// GEMM1^T: wave = 32h x 128 samples (4 N-tiles), A=W1 frags in regs (4 kst),
//   B=x from sX -> 16 ds_read + 16 MFMA per g. D[h][sample]: reg r ->
//   h = wv*32 + (r&3)+8*(r>>2)+4*hi (4 runs of 4 consecutive h -> b64 packs).
// GEMM2: wave = 32 samples x 32 j (rt=wv>>1, ct=wv&1), K=256 -> 16 ksteps,
//   dual accumulators (even/odd kst) to break the dependent-MFMA chain;
//   32 ds_read + 16 MFMA per g. vs 16x16 structure: ds_read/CU-work -25%.
// Counted-vmcnt: issue {sX glds x2, w1f x4, sW glds x4}; B1 waits vmcnt(4)
// so the 4 sW glds stay in flight under GEMM1; B2 drains before GEMM2.
__global__ __launch_bounds__(512, 2) void k_main(const unsigned short* __restrict__ xb,   // [4096][512]
                                                 const unsigned short* __restrict__ w1t,  // [2048][512] = W1^T
                                                 const unsigned short* __restrict__ w2t,  // [512][2048] = W2^T
                                                 const float* __restrict__ b1,            // [2048]
                                                 __half* __restrict__ P) {                // [NCH][4096][512] fp16
    __shared__ unsigned short sX[TM * 64];        // x_g  [sample][k]  16KB (swz ^row&7)
    __shared__ unsigned short sW[64 * 256];       // W2_g [j][k]       32KB (swz ^row&7)
    __shared__ unsigned short sH[TM * 256];       // h    [sample][h]  64KB (swz ^row&7)

    const int chunk = blockIdx.x;                 // 0..7
    const int row0  = blockIdx.y * TM;
    const int hbase = chunk * HC;

    const int t    = threadIdx.x;
    const int lane = t & 63, wv = t >> 6;         // wave 0..7
    const int l32  = lane & 31, hi = lane >> 5;

    // bias folded into acc1 init: h_local = wv*32 + (r&3) + 8*(r>>2) + 4*hi
    f32x16 bv;
    #pragma unroll
    for (int r = 0; r < 16; ++r)
        bv[r] = b1[hbase + wv * 32 + (r & 3) + 8 * (r >> 2) + 4 * hi];
    f32x16 acc1[4];
    #pragma unroll
    for (int nt = 0; nt < 4; ++nt) acc1[nt] = bv;

    const int rt = wv >> 1;                       // GEMM2 sample-tile (0..3)
    const int ct = wv & 1;                        // GEMM2 j-tile (0..1)
    __half* Pc = P + (size_t)chunk * (NROWS * ODIM);
    const unsigned short* w1p = w1t + (size_t)(hbase + wv * 32 + l32) * 512 + hi * 8;

    for (int g = 0; g < NG; ++g) {
        // B0: prev GEMM2 LDS reads done (lgkm only; P-stores stay in flight)
        asm volatile("s_waitcnt lgkmcnt(0)" ::: "memory");
        __builtin_amdgcn_s_barrier();
        __builtin_amdgcn_sched_barrier(0);

        // stage x_g (16KB), W1 frags (regs), W2_g (32KB) — in this issue order
        #pragma unroll
        for (int i = 0; i < 2; ++i) {
            int id = i * 512 + t;                 // 0..1023
            int row = id >> 3, gb = id & 7;
            glds16(xb + (size_t)(row0 + row) * 512 + g * 64 + ((gb ^ (row & 7)) << 3),
                   sX + (size_t)(id & ~63) * 8);
        }
        short8 w1f[4];
        #pragma unroll
        for (int kst = 0; kst < 4; ++kst)
            w1f[kst] = *reinterpret_cast<const short8*>(w1p + g * 64 + kst * 16);
        #pragma unroll
        for (int i = 0; i < 4; ++i) {
            int id = i * 512 + t;                 // 0..2047
            int jr = id >> 5, cb = id & 31;       // jr 0..63, cb 0..31
            glds16(w2t + (size_t)(g * 64 + jr) * 2048 + hbase + ((cb ^ (jr & 7)) << 3),
                   sW + (size_t)(id & ~63) * 8);
        }
        // B1: sX + w1f complete; 4 sW glds remain in flight across the barrier
        asm volatile("s_waitcnt vmcnt(4) lgkmcnt(0)" ::: "memory");
        __builtin_amdgcn_s_barrier();
        __builtin_amdgcn_sched_barrier(0);

        // ---- GEMM1^T: acc1[nt] += W1_g(A) x x_g(B) -> D[h][sample] ----
        #pragma unroll
        for (int kst = 0; kst < 4; ++kst) {
            #pragma unroll
            for (int nt = 0; nt < 4; ++nt) {
                int row = nt * 32 + l32;
                short8 xf = *reinterpret_cast<const short8*>(
                    &sX[row * 64 + (((kst * 2 + hi) ^ (row & 7)) << 3)]);
                acc1[nt] = __builtin_amdgcn_mfma_f32_32x32x16_bf16(
                    w1f[kst], xf, acc1[nt], 0, 0, 0);
            }
        }

        // ---- h = relu(acc1) -> sH via v_cvt_pk_bf16_f32 (RNE) ----
        // reg run q: h0 = wv*32 + 8*q + 4*hi, regs 4q..4q+3 = h0..h0+3
        #pragma unroll
        for (int nt = 0; nt < 4; ++nt) {
            const int sample = nt * 32 + l32;
            #pragma unroll
            for (int q = 0; q < 4; ++q) {
                float m0 = fmaxf(acc1[nt][q * 4 + 0], 0.f);
                float m1 = fmaxf(acc1[nt][q * 4 + 1], 0.f);
                float m2 = fmaxf(acc1[nt][q * 4 + 2], 0.f);
                float m3 = fmaxf(acc1[nt][q * 4 + 3], 0.f);
                unsigned int p0, p1;
                asm("v_cvt_pk_bf16_f32 %0, %1, %2" : "=v"(p0) : "v"(m0), "v"(m1));
                asm("v_cvt_pk_bf16_f32 %0, %1, %2" : "=v"(p1) : "v"(m2), "v"(m3));
                uint2 pk = { p0, p1 };
                *reinterpret_cast<uint2*>(
                    &sH[sample * 256 + (((wv * 4 + q) ^ (sample & 7)) << 3) + hi * 4]) = pk;
            }
        }
        // B2: sW glds drained + sH writes visible
        asm volatile("s_waitcnt vmcnt(0) lgkmcnt(0)" ::: "memory");
        __builtin_amdgcn_s_barrier();
        __builtin_amdgcn_sched_barrier(0);

        // ---- GEMM2: P_g = h @ W2_g  (K=256 -> 16 ksteps of K=16) ----
        // D[sample][j]: col=l32 -> j, rows -> samples. Dual acc breaks chain.
        f32x16 a2a, a2b;
        #pragma unroll
        for (int r = 0; r < 16; ++r) { a2a[r] = 0.f; a2b[r] = 0.f; }
        const int arow = rt * 32 + l32;
        const int brow = ct * 32 + l32;
        #pragma unroll
        for (int kp = 0; kp < 8; ++kp) {
            {
                int gk = kp * 4 + hi;             // kst = 2*kp (even)
                short8 a = *reinterpret_cast<const short8*>(
                    &sH[arow * 256 + ((gk ^ (arow & 7)) << 3)]);
                short8 b = *reinterpret_cast<const short8*>(
                    &sW[brow * 256 + ((gk ^ (brow & 7)) << 3)]);
                a2a = __builtin_amdgcn_mfma_f32_32x32x16_bf16(a, b, a2a, 0, 0, 0);
            }
            {
                int gk = kp * 4 + 2 + hi;         // kst = 2*kp+1 (odd)
                short8 a = *reinterpret_cast<const short8*>(
                    &sH[arow * 256 + ((gk ^ (arow & 7)) << 3)]);
                short8 b = *reinterpret_cast<const short8*>(
                    &sW[brow * 256 + ((gk ^ (brow & 7)) << 3)]);
                a2b = __builtin_amdgcn_mfma_f32_32x32x16_bf16(a, b, a2b, 0, 0, 0);
            }
        }
        #pragma unroll
        for (int r = 0; r < 16; ++r) {
            float v = a2a[r] + a2b[r];
            Pc[(size_t)(row0 + rt * 32 + (r & 3) + 8 * (r >> 2) + 4 * hi) * 512 +
               g * 64 + ct * 32 + l32] = __float2half(v);
        }
    }
}

// ---- Kernel 2: out = sum_c P[c] + b2 ----
__global__ __launch_bounds__(256) void k_reduce(const __half* __restrict__ P,
                                                const float* __restrict__ b2,
                                                float* __restrict__ out) {
    int t = blockIdx.x * 256 + threadIdx.x;       // 524288 threads, 4 outputs each
    size_t f = (size_t)t * 4;
    int j = (int)(f & 511);
    float4 s = *reinterpret_cast<const float4*>(&b2[j]);
    #pragma unroll
    for (int c = 0; c < NCH; ++c) {
        const __half2* p = reinterpret_cast<const __half2*>(P + (size_t)c * (NROWS * ODIM) + f);
        float2 a = __half22float2(p[0]);
        float2 b = __half22float2(p[1]);
        s.x += a.x; s.y += a.y; s.z += b.x; s.w += b.y;
    }
    *reinterpret_cast<float4*>(&out[f]) = s;
}

extern "C" void kernel_launch(void* const* d_in, const int* in_sizes, int n_in,
                              void* d_out, int out_size, void* d_ws, size_t ws_size,
                              hipStream_t stream) {
    const float* x  = (const float*)d_in[0];
    const float* W1 = (const float*)d_in[1];
    const float* b1 = (const float*)d_in[2];
    const float* W2 = (const float*)d_in[3];
    const float* b2 = (const float*)d_in[4];
    float* out = (float*)d_out;

    unsigned short* xb  = (unsigned short*)d_ws;                          // 4 MB
    unsigned short* w1t = (unsigned short*)((char*)d_ws + (4u << 20));    // 2 MB
    unsigned short* w2t = (unsigned short*)((char*)d_ws + (6u << 20));    // 2 MB
    __half*         P   = (__half*)((char*)d_ws + (8u << 20));            // 32 MB fp16

    k_prep<<<1536, 256, 0, stream>>>(x, W1, W2, xb, w1t, w2t);
    k_main<<<dim3(NCH, NROWS / TM), 512, 0, stream>>>(xb, w1t, w2t, b1, P);
    k_reduce<<<2048, 256, 0, stream>>>(P, b2, out);
}